// Round 14
// baseline (1054.465 us; speedup 1.0000x reference)
//
#include <hip/hip_runtime.h>

#define NN 100000
#define NE 3200000
#define F 256
#define NCLS 40
#define NC 391              // coarse buckets of 256 dst nodes: 391*256 >= NN
#define NBLK_H 256          // histogram/scatter blocks; NE/NBLK_H = 12500
#define EPB (NE / NBLK_H)   // 12500 edges per block slice
#define CW 25000            // cnt_out words (NN/4, byte-packed)

using h4 = __attribute__((ext_vector_type(4))) _Float16;
using h8 = __attribute__((ext_vector_type(8))) _Float16;
using f4 = __attribute__((ext_vector_type(4))) float;

// ---------------- LDS-privatized histogram (512 thr): out-degree u8 + coarse buckets ----------------
__global__ __launch_bounds__(512) void hist_k(const int* __restrict__ src,
                                              const int* __restrict__ dst,
                                              unsigned* __restrict__ pcnt,
                                              unsigned* __restrict__ pcc) {
    __shared__ unsigned hsrc[CW];     // 100 KB
    __shared__ unsigned hc[NC];
    int t = threadIdx.x, b = blockIdx.x;
    for (int i = t; i < CW; i += 512) hsrc[i] = 0;
    for (int i = t; i < NC; i += 512) hc[i] = 0;
    __syncthreads();
    int beg = b * EPB, end = beg + EPB;
    for (int e = beg + t; e < end; e += 512) {
        int s = src[e];
        atomicAdd(&hsrc[s >> 2], 1u << (8 * (s & 3)));
        atomicAdd(&hc[dst[e] >> 8], 1u);
    }
    __syncthreads();
    unsigned* pc = pcnt + (size_t)b * CW;
    for (int i = t; i < CW; i += 512) pc[i] = hsrc[i];
    unsigned* pb = pcc + (size_t)b * NC;
    for (int i = t; i < NC; i += 512) pb[i] = hc[i];
}

// ---------------- stage A: per-group partial sums (atomic-free) ----------------
__global__ __launch_bounds__(256) void redA_k(const unsigned* __restrict__ pcnt,
                                              unsigned* __restrict__ pl,
                                              unsigned* __restrict__ ph) {
    int w = blockIdx.x * 256 + threadIdx.x;
    if (w >= CW) return;
    int g = blockIdx.y;
    unsigned lo = 0, hi = 0;
    for (int b = g * 32; b < g * 32 + 32; b++) {
        unsigned v = pcnt[(size_t)b * CW + w];
        lo += (v & 255u) | (((v >> 8) & 255u) << 16);
        hi += ((v >> 16) & 255u) | ((v >> 24) << 16);
    }
    pl[(size_t)g * CW + w] = lo;
    ph[(size_t)g * CW + w] = hi;
}

// ---------------- stage B: sum 8 groups, unpack -> nout ----------------
__global__ void nout2_k(const unsigned* __restrict__ pl, const unsigned* __restrict__ ph,
                        float* __restrict__ nout) {
    int w = blockIdx.x * blockDim.x + threadIdx.x;
    if (w >= CW) return;
    unsigned lo = 0, hi = 0;
#pragma unroll
    for (int g = 0; g < 8; g++) { lo += pl[(size_t)g * CW + w]; hi += ph[(size_t)g * CW + w]; }
    float4 o;
    o.x = rsqrtf(fmaxf((float)(lo & 0xFFFFu), 1.f));
    o.y = rsqrtf(fmaxf((float)(lo >> 16), 1.f));
    o.z = rsqrtf(fmaxf((float)(hi & 0xFFFFu), 1.f));
    o.w = rsqrtf(fmaxf((float)(hi >> 16), 1.f));
    *(float4*)(nout + w * 4) = o;
}

// ---------------- per-bucket scan over blocks ----------------
__global__ __launch_bounds__(256) void offsets_k(const unsigned* __restrict__ pcc,
                                                 unsigned* __restrict__ curoff,
                                                 unsigned* __restrict__ totals) {
    __shared__ unsigned sh[256];
    int c = blockIdx.x, t = threadIdx.x;
    unsigned v = pcc[(size_t)t * NC + c];
    sh[t] = v;
    __syncthreads();
    for (int off = 1; off < 256; off <<= 1) {
        unsigned x = (t >= off) ? sh[t - off] : 0;
        __syncthreads();
        sh[t] += x;
        __syncthreads();
    }
    curoff[(size_t)t * NC + c] = sh[t] - v;
    if (t == 255) totals[c] = sh[255];
}

// ---------------- exclusive scan of coarse totals -> cbase[NC+1] ----------------
__global__ __launch_bounds__(512) void base_k(const unsigned* __restrict__ totals,
                                              int* __restrict__ cbase) {
    __shared__ unsigned sh[512];
    int t = threadIdx.x;
    unsigned v = (t < NC) ? totals[t] : 0;
    sh[t] = v;
    __syncthreads();
    for (int off = 1; off < 512; off <<= 1) {
        unsigned x = (t >= off) ? sh[t - off] : 0;
        __syncthreads();
        sh[t] += x;
        __syncthreads();
    }
    if (t < NC) cbase[t] = (int)(sh[t] - v);
    if (t == 0) cbase[NC] = NE;
}

// ---------------- pass 1: scatter into coarse regions, LDS cursors (512 thr) ----------------
__global__ __launch_bounds__(512) void p1scat_k(const int* __restrict__ src,
                                                const int* __restrict__ dst,
                                                const int* __restrict__ cbase,
                                                const unsigned* __restrict__ curoff,
                                                unsigned* __restrict__ ebuf) {
    __shared__ int cur[NC];
    int t = threadIdx.x, b = blockIdx.x;
    for (int i = t; i < NC; i += 512)
        cur[i] = cbase[i] + (int)curoff[(size_t)b * NC + i];
    __syncthreads();
    int beg = b * EPB, end = beg + EPB;
    for (int e = beg + t; e < end; e += 512) {
        int d = dst[e];
        int p = atomicAdd(&cur[d >> 8], 1);
        ebuf[p] = (unsigned)src[e] | ((unsigned)(d & 255) << 17);
    }
}

// ---------------- pass 2: per-bucket sort by (fine_dst, src-range) -> csr_src, row_ptr, nin ----------------
// key = fine_dst<<5 | (src>>12); src>>12 in [0,24]. Edge lists per node come out
// sorted by src-range -> enables the range-swept aggregation (L2 temporal blocking).
__global__ __launch_bounds__(512) void p2build_k(const int* __restrict__ cbase,
                                                 const unsigned* __restrict__ ebuf,
                                                 int* __restrict__ csr_src,
                                                 int* __restrict__ row_ptr,
                                                 float* __restrict__ nin) {
    __shared__ int cnt[8192];        // 32 KB: key counters -> exclusive scan -> cursors
    __shared__ int sh[512];
    int c = blockIdx.x, t = threadIdx.x;
    int beg = cbase[c], end = cbase[c + 1];
    for (int i = t; i < 8192; i += 512) cnt[i] = 0;
    __syncthreads();
    for (int e = beg + t; e < end; e += 512) {
        unsigned w = ebuf[e];
        int key = (int)(((w >> 17) & 255u) << 5) | (int)((w & 0x1FFFFu) >> 12);
        atomicAdd(&cnt[key], 1);
    }
    __syncthreads();
    // in-place exclusive scan of cnt[0..8191]: 16 values per thread
    int loc[16];
    int base16 = t * 16;
    int lsum = 0;
#pragma unroll
    for (int i = 0; i < 16; i++) { loc[i] = cnt[base16 + i]; lsum += loc[i]; }
    sh[t] = lsum;
    __syncthreads();
    for (int off = 1; off < 512; off <<= 1) {
        int x = (t >= off) ? sh[t - off] : 0;
        __syncthreads();
        sh[t] += x;
        __syncthreads();
    }
    int run = sh[t] - lsum;
#pragma unroll
    for (int i = 0; i < 16; i++) { cnt[base16 + i] = run; run += loc[i]; }
    __syncthreads();
    // row_ptr + nin from scan (before cursors mutate)
    if (t < 256) {
        int node = c * 256 + t;
        int start = cnt[t << 5];
        int next  = (t == 255) ? (end - beg) : cnt[(t + 1) << 5];
        if (node < NN) {
            row_ptr[node] = beg + start;
            nin[node] = rsqrtf(fmaxf((float)(next - start), 1.f));
        }
    }
    if (c == 0 && t == 0) row_ptr[NN] = NE;
    __syncthreads();
    // scatter: cnt[] now acts as cursors
    for (int e = beg + t; e < end; e += 512) {
        unsigned w = ebuf[e];
        int s = (int)(w & 0x1FFFFu);
        int key = (int)(((w >> 17) & 255u) << 5) | (s >> 12);
        int p = atomicAdd(&cnt[key], 1);
        csr_src[beg + p] = s;
    }
}

// ---------------- fused conversions: features*nout -> fp16; weights -> fp16^T PRE-SWIZZLED ----------------
__global__ void conv_fused_k(const float4* __restrict__ fin, const float* __restrict__ nout,
                             h4* __restrict__ fout,
                             const float* __restrict__ W0, const float* __restrict__ W1,
                             const float* __restrict__ W2,
                             _Float16* __restrict__ Wt0, _Float16* __restrict__ Wt1,
                             _Float16* __restrict__ Wt2) {
    int i = blockIdx.x * blockDim.x + threadIdx.x;
    const int N4 = NN * 64;
    if (i < N4) {
        float s = nout[i >> 6];
        float4 v = fin[i];
        h4 o;
        o[0] = (_Float16)(v.x * s);
        o[1] = (_Float16)(v.y * s);
        o[2] = (_Float16)(v.z * s);
        o[3] = (_Float16)(v.w * s);
        fout[i] = o;
    } else {
        int j = i - N4;
        if (j < 65536) {
            int n = j >> 8, k = (j & 255) ^ ((n & 7) << 3);
            Wt0[j] = (_Float16)W0[k * 256 + n];
        } else if (j < 131072) {
            int jj = j - 65536;
            int n = jj >> 8, k = (jj & 255) ^ ((n & 7) << 3);
            Wt1[jj] = (_Float16)W1[k * 256 + n];
        } else if (j < 147456) {
            int jj = j - 131072;
            int n = jj >> 8, k = (jj & 255) ^ ((n & 7) << 3);
            Wt2[jj] = (n < NCLS) ? (_Float16)W2[k * NCLS + n] : (_Float16)0.0f;
        }
    }
}

// ---------------- SRC-RANGE-SWEPT aggregation (A/B test vs agg256h_k) ----------------
// 8 nodes per wave; each half-wave (32 lanes, h8 cols) owns 4 node slots with fp32
// accumulators in registers. All waves sweep src-ranges 0..24 in the same order, so
// the chip-wide working set at any moment is one 2 MB h-slice -> per-XCD L2-resident.
__global__ __launch_bounds__(256) void agg256sw_k(
        const int* __restrict__ row_ptr, const int* __restrict__ csr_src,
        const _Float16* __restrict__ h, _Float16* __restrict__ agg, int nN) {
    int wid  = (blockIdx.x * blockDim.x + threadIdx.x) >> 6;
    int lane = threadIdx.x & 63;
    int half = lane >> 5, col = lane & 31;
    int node0 = wid * 8;
    if (node0 >= nN) return;

    int c0, c1, c2, c3, e0, e1, e2, e3;
    {
        int nd;
        nd = node0 + 0 + half; if (nd < nN) { c0 = row_ptr[nd]; e0 = row_ptr[nd + 1]; } else { c0 = e0 = 0; }
        nd = node0 + 2 + half; if (nd < nN) { c1 = row_ptr[nd]; e1 = row_ptr[nd + 1]; } else { c1 = e1 = 0; }
        nd = node0 + 4 + half; if (nd < nN) { c2 = row_ptr[nd]; e2 = row_ptr[nd + 1]; } else { c2 = e2 = 0; }
        nd = node0 + 6 + half; if (nd < nN) { c3 = row_ptr[nd]; e3 = row_ptr[nd + 1]; } else { c3 = e3 = 0; }
    }
    f4 a0[2] = {(f4){0,0,0,0},(f4){0,0,0,0}}, a1[2] = {(f4){0,0,0,0},(f4){0,0,0,0}};
    f4 a2[2] = {(f4){0,0,0,0},(f4){0,0,0,0}}, a3[2] = {(f4){0,0,0,0},(f4){0,0,0,0}};

    for (int r = 0; r < 25; r++) {
        while (true) {
            bool g0 = false, g1 = false, g2 = false, g3 = false;
            int s0 = 0, s1 = 0, s2 = 0, s3 = 0;
            if (c0 < e0) { s0 = csr_src[c0]; g0 = ((s0 >> 12) == r); }
            if (c1 < e1) { s1 = csr_src[c1]; g1 = ((s1 >> 12) == r); }
            if (c2 < e2) { s2 = csr_src[c2]; g2 = ((s2 >> 12) == r); }
            if (c3 < e3) { s3 = csr_src[c3]; g3 = ((s3 >> 12) == r); }
            if (!(g0 | g1 | g2 | g3)) break;
            h8 v0, v1, v2, v3;
            if (g0) { v0 = *(const h8*)(h + (size_t)s0 * F + col * 8); c0++; }
            if (g1) { v1 = *(const h8*)(h + (size_t)s1 * F + col * 8); c1++; }
            if (g2) { v2 = *(const h8*)(h + (size_t)s2 * F + col * 8); c2++; }
            if (g3) { v3 = *(const h8*)(h + (size_t)s3 * F + col * 8); c3++; }
#pragma unroll
            for (int j = 0; j < 8; j++) {
                if (g0) a0[j >> 2][j & 3] += (float)v0[j];
                if (g1) a1[j >> 2][j & 3] += (float)v1[j];
                if (g2) a2[j >> 2][j & 3] += (float)v2[j];
                if (g3) a3[j >> 2][j & 3] += (float)v3[j];
            }
        }
    }
    // write out: each half covers the full 256-wide row of its 4 nodes
    {
        int nd;
        h8 o;
        nd = node0 + 0 + half;
        if (nd < nN) {
#pragma unroll
            for (int j = 0; j < 8; j++) o[j] = (_Float16)a0[j >> 2][j & 3];
            *(h8*)(agg + (size_t)nd * F + col * 8) = o;
        }
        nd = node0 + 2 + half;
        if (nd < nN) {
#pragma unroll
            for (int j = 0; j < 8; j++) o[j] = (_Float16)a1[j >> 2][j & 3];
            *(h8*)(agg + (size_t)nd * F + col * 8) = o;
        }
        nd = node0 + 4 + half;
        if (nd < nN) {
#pragma unroll
            for (int j = 0; j < 8; j++) o[j] = (_Float16)a2[j >> 2][j & 3];
            *(h8*)(agg + (size_t)nd * F + col * 8) = o;
        }
        nd = node0 + 6 + half;
        if (nd < nN) {
#pragma unroll
            for (int j = 0; j < 8; j++) o[j] = (_Float16)a3[j >> 2][j & 3];
            *(h8*)(agg + (size_t)nd * F + col * 8) = o;
        }
    }
}

// ---------------- CSR aggregation, 256-wide (control; order-insensitive) ----------------
__global__ __launch_bounds__(256) void agg256h_k(
        const int* __restrict__ row_ptr, const int* __restrict__ csr_src,
        const _Float16* __restrict__ h, _Float16* __restrict__ agg, int nN) {
    int node = (blockIdx.x * blockDim.x + threadIdx.x) >> 6;
    int lane = threadIdx.x & 63;
    if (node >= nN) return;
    int half = lane >> 5, col = lane & 31;
    int beg = row_ptr[node], end = row_ptr[node + 1];
    f4 a[4][2];
#pragma unroll
    for (int u = 0; u < 4; u++) { a[u][0] = (f4){0,0,0,0}; a[u][1] = (f4){0,0,0,0}; }
    int e = beg;
    for (; e + 7 < end; e += 8) {
        int s[4];
#pragma unroll
        for (int u = 0; u < 4; u++) s[u] = csr_src[e + 2 * u + half];
        h8 v[4];
#pragma unroll
        for (int u = 0; u < 4; u++)
            v[u] = *(const h8*)(h + (size_t)s[u] * F + col * 8);
#pragma unroll
        for (int u = 0; u < 4; u++)
#pragma unroll
            for (int j = 0; j < 8; j++) a[u][j >> 2][j & 3] += (float)v[u][j];
    }
    for (int t = e + half; t < end; t += 2) {
        h8 v = *(const h8*)(h + (size_t)csr_src[t] * F + col * 8);
#pragma unroll
        for (int j = 0; j < 8; j++) a[0][j >> 2][j & 3] += (float)v[j];
    }
    float r[8];
#pragma unroll
    for (int j = 0; j < 8; j++)
        r[j] = (a[0][j >> 2][j & 3] + a[1][j >> 2][j & 3])
             + (a[2][j >> 2][j & 3] + a[3][j >> 2][j & 3]);
#pragma unroll
    for (int j = 0; j < 8; j++) r[j] += __shfl_xor(r[j], 32);
    if (half == 0) {
        h8 o;
#pragma unroll
        for (int j = 0; j < 8; j++) o[j] = (_Float16)r[j];
        *(h8*)(agg + (size_t)node * F + col * 8) = o;
    }
}

// ---------------- CSR aggregation, 64-wide: 8 lanes/edge + final epilogue ----------------
__global__ __launch_bounds__(256) void agg64h_k(
        const int* __restrict__ row_ptr, const int* __restrict__ csr_src,
        const _Float16* __restrict__ t3, const float* __restrict__ nin,
        const float* __restrict__ b2, float* __restrict__ out, int nN) {
    int node = (blockIdx.x * blockDim.x + threadIdx.x) >> 6;
    int lane = threadIdx.x & 63;
    if (node >= nN) return;
    int grp = lane >> 3, c = lane & 7;
    int beg = row_ptr[node], end = row_ptr[node + 1];
    float a0[8], a1[8];
#pragma unroll
    for (int j = 0; j < 8; j++) { a0[j] = 0.f; a1[j] = 0.f; }
    int e = beg;
    for (; e + 15 < end; e += 16) {
        int s0 = csr_src[e + grp], s1 = csr_src[e + 8 + grp];
        h8 v0 = *(const h8*)(t3 + (size_t)s0 * 64 + c * 8);
        h8 v1 = *(const h8*)(t3 + (size_t)s1 * 64 + c * 8);
#pragma unroll
        for (int j = 0; j < 8; j++) { a0[j] += (float)v0[j]; a1[j] += (float)v1[j]; }
    }
    for (int t = e + grp; t < end; t += 8) {
        h8 v = *(const h8*)(t3 + (size_t)csr_src[t] * 64 + c * 8);
#pragma unroll
        for (int j = 0; j < 8; j++) a0[j] += (float)v[j];
    }
    float r[8];
#pragma unroll
    for (int j = 0; j < 8; j++) {
        r[j] = a0[j] + a1[j];
        r[j] += __shfl_xor(r[j], 8);
        r[j] += __shfl_xor(r[j], 16);
        r[j] += __shfl_xor(r[j], 32);
    }
    if (grp == 0 && c < 5) {
        float ni = nin[node];
        float4 o;
        o.x = r[0] * ni + b2[c * 8 + 0];
        o.y = r[1] * ni + b2[c * 8 + 1];
        o.z = r[2] * ni + b2[c * 8 + 2];
        o.w = r[3] * ni + b2[c * 8 + 3];
        *(float4*)(out + (size_t)node * NCLS + c * 8) = o;
        o.x = r[4] * ni + b2[c * 8 + 4];
        o.y = r[5] * ni + b2[c * 8 + 5];
        o.z = r[6] * ni + b2[c * 8 + 6];
        o.w = r[7] * ni + b2[c * 8 + 7];
        *(float4*)(out + (size_t)node * NCLS + c * 8 + 4) = o;
    }
}

// ---------------- layer-0 GEMM: LDS-resident, 1024 thr, pre-swizzled Wt ----------------
__global__ __launch_bounds__(1024) void gemm0_k(
        const _Float16* __restrict__ A, const _Float16* __restrict__ Wt,
        _Float16* __restrict__ C, int M,
        const float* __restrict__ nin, const float* __restrict__ nout,
        const float* __restrict__ bias) {
    __shared__ _Float16 lds[256 * 256];      // 128 KiB
    char* ldsb = (char*)lds;
    const int tid  = threadIdx.x;
    const int lane = tid & 63;
    const int w    = tid >> 6;
    const int row0 = blockIdx.x * 256;

#pragma unroll
    for (int i = 0; i < 8; i++) {
        int idx = (i * 1024 + tid) * 8;
        *(h8*)(ldsb + idx * 2) = *(const h8*)(Wt + idx);
    }

    int arow = row0 + w * 16 + (lane & 15);
    if (arow >= M) arow = M - 1;
    const _Float16* Ap = A + (size_t)arow * 256 + (lane >> 4) * 8;
    h8 areg[8];
#pragma unroll
    for (int i = 0; i < 8; i++) areg[i] = *(const h8*)(Ap + i * 32);

    __syncthreads();

    f4 acc[16];
#pragma unroll
    for (int n = 0; n < 16; n++) acc[n] = (f4){0.f, 0.f, 0.f, 0.f};

#pragma unroll
    for (int k0 = 0; k0 < 8; k0++) {
        int kb = (k0 * 32 + (lane >> 4) * 8) * 2;
#pragma unroll
        for (int n = 0; n < 16; n++) {
            int r    = n * 16 + (lane & 15);
            int byte = r * 512 + kb;
            h8 bf = *(const h8*)(ldsb + (byte ^ ((r & 7) << 4)));
            acc[n] = __builtin_amdgcn_mfma_f32_16x16x32_f16(areg[k0], bf, acc[n], 0, 0, 0);
        }
    }

    __syncthreads();

    const int g  = lane >> 4;
    const int rb = row0 + w * 16 + g * 4;
    float si[4], so[4];
#pragma unroll
    for (int r = 0; r < 4; r++) {
        int rr = rb + r; if (rr >= M) rr = M - 1;
        si[r] = nin[rr];
        so[r] = nout[rr];
    }
    char* warea = ldsb + w * 8192;
#pragma unroll
    for (int n = 0; n < 16; n++) {
        float bb = bias[n * 16 + (lane & 15)];
#pragma unroll
        for (int r = 0; r < 4; r++) {
            float x = fmaxf(acc[n][r] * si[r] + bb, 0.f) * so[r];
            int lrow = g * 4 + r;
            int lcol = n * 16 + (lane & 15);
            *(_Float16*)(warea + (size_t)(lrow * 256 + lcol) * 2) = (_Float16)x;
        }
    }

    _Float16* Crow = C + (size_t)(row0 + w * 16) * 256;
#pragma unroll
    for (int i = 0; i < 8; i++) {
        int off  = i * 1024 + lane * 16;
        int lrow = off >> 9;
        int grow = row0 + w * 16 + lrow;
        h8 v = *(const h8*)(warea + off);
        if (grow < M) *(h8*)((char*)Crow + off) = v;
    }
}

// ---------------- FUSED layer-1 GEMM + layer-2 GEMM ----------------
__global__ __launch_bounds__(1024) void gemm12_k(
        const _Float16* __restrict__ A, const _Float16* __restrict__ Wt1s,
        const _Float16* __restrict__ Wt2s, _Float16* __restrict__ t3, int M,
        const float* __restrict__ nin, const float* __restrict__ nout,
        const float* __restrict__ bias) {
    __shared__ _Float16 lds[256 * 256];      // 128 KiB
    char* ldsb = (char*)lds;
    const int tid  = threadIdx.x;
    const int lane = tid & 63;
    const int w    = tid >> 6;
    const int row0 = blockIdx.x * 256;

#pragma unroll
    for (int i = 0; i < 8; i++) {
        int idx = (i * 1024 + tid) * 8;
        *(h8*)(ldsb + idx * 2) = *(const h8*)(Wt1s + idx);
    }

    int arow = row0 + w * 16 + (lane & 15);
    if (arow >= M) arow = M - 1;
    const _Float16* Ap = A + (size_t)arow * 256 + (lane >> 4) * 8;
    h8 areg[8];
#pragma unroll
    for (int i = 0; i < 8; i++) areg[i] = *(const h8*)(Ap + i * 32);

    __syncthreads();

    f4 acc[16];
#pragma unroll
    for (int n = 0; n < 16; n++) acc[n] = (f4){0.f, 0.f, 0.f, 0.f};
#pragma unroll
    for (int k0 = 0; k0 < 8; k0++) {
        int kb = (k0 * 32 + (lane >> 4) * 8) * 2;
#pragma unroll
        for (int n = 0; n < 16; n++) {
            int r    = n * 16 + (lane & 15);
            int byte = r * 512 + kb;
            h8 bf = *(const h8*)(ldsb + (byte ^ ((r & 7) << 4)));
            acc[n] = __builtin_amdgcn_mfma_f32_16x16x32_f16(areg[k0], bf, acc[n], 0, 0, 0);
        }
    }

    __syncthreads();

    const int g  = lane >> 4;
    const int rb = row0 + w * 16 + g * 4;
    float si[4], so[4];
#pragma unroll
    for (int r = 0; r < 4; r++) {
        int rr = rb + r; if (rr >= M) rr = M - 1;
        si[r] = nin[rr];
        so[r] = nout[rr];
    }
    char* warea = ldsb + w * 8192;
#pragma unroll
    for (int n = 0; n < 16; n++) {
        float bb = bias[n * 16 + (lane & 15)];
#pragma unroll
        for (int r = 0; r < 4; r++) {
            float x = fmaxf(acc[n][r] * si[r] + bb, 0.f) * so[r];
            int lrow = g * 4 + r;
            int lcol = n * 16 + (lane & 15);
            int byte = lrow * 512 + lcol * 2;
            *(_Float16*)(warea + (byte ^ ((lrow & 7) << 4))) = (_Float16)x;
        }
    }

    h8 areg2[8];
    {
        int lr = lane & 15;
#pragma unroll
        for (int k0 = 0; k0 < 8; k0++) {
            int byte = lr * 512 + k0 * 64 + (lane >> 4) * 16;
            areg2[k0] = *(const h8*)(warea + (byte ^ ((lr & 7) << 4)));
        }
    }
    __syncthreads();

#pragma unroll
    for (int i = 0; i < 2; i++) {
        int idx = (i * 1024 + tid) * 8;
        *(h8*)(ldsb + idx * 2) = *(const h8*)(Wt2s + idx);
    }
    __syncthreads();

    f4 acc2[4];
#pragma unroll
    for (int n = 0; n < 4; n++) acc2[n] = (f4){0.f, 0.f, 0.f, 0.f};
#pragma unroll
    for (int k0 = 0; k0 < 8; k0++) {
        int kb = k0 * 64 + (lane >> 4) * 16;
#pragma unroll
        for (int n = 0; n < 4; n++) {
            int r    = n * 16 + (lane & 15);
            int byte = r * 512 + kb;
            h8 bf = *(const h8*)(ldsb + (byte ^ ((r & 7) << 4)));
            acc2[n] = __builtin_amdgcn_mfma_f32_16x16x32_f16(areg2[k0], bf, acc2[n], 0, 0, 0);
        }
    }

    char* tarea = ldsb + 32768 + w * 2048;
#pragma unroll
    for (int n = 0; n < 4; n++)
#pragma unroll
        for (int r = 0; r < 4; r++) {
            int lrow = g * 4 + r;
            int c = n * 16 + (lane & 15);
            *(_Float16*)(tarea + lrow * 128 + c * 2) = (_Float16)acc2[n][r];
        }
#pragma unroll
    for (int i = 0; i < 2; i++) {
        int off  = i * 1024 + lane * 16;
        int lrow = off >> 7;
        int grow = row0 + w * 16 + lrow;
        h8 v = *(const h8*)(tarea + off);
        if (grow < M) *(h8*)((char*)t3 + (size_t)grow * 128 + (off & 127)) = v;
    }
}

extern "C" void kernel_launch(void* const* d_in, const int* in_sizes, int n_in,
                              void* d_out, int out_size, void* d_ws, size_t ws_size,
                              hipStream_t stream) {
    const float* features = (const float*)d_in[0];
    const int*   src      = (const int*)d_in[1];
    const int*   dst      = (const int*)d_in[2];
    const float* W0       = (const float*)d_in[3];
    const float* b0       = (const float*)d_in[4];
    const float* W1       = (const float*)d_in[5];
    const float* b1       = (const float*)d_in[6];
    const float* W2       = (const float*)d_in[7];
    const float* b2       = (const float*)d_in[8];
    float* out = (float*)d_out;

    // ---- workspace carve (16B-aligned sections) ----
    char* ws = (char*)d_ws;
    const size_t H_BYTES = (size_t)NN * F * 2;             // 51.2 MB
    _Float16* hA   = (_Float16*)(ws);
    _Float16* hB   = (_Float16*)(ws + H_BYTES);
    _Float16* t3h  = (_Float16*)(ws + 2 * H_BYTES);        // [NN,64] fp16
    char* q = ws + 2 * H_BYTES + (size_t)NN * 64 * 2;
    int* csr_src    = (int*)q;               q += (size_t)NE * 4;             // 12.8 MB
    unsigned* ebuf  = (unsigned*)q;          q += (size_t)NE * 4;             // 12.8 MB
    unsigned* pcnt  = (unsigned*)q;          q += (size_t)NBLK_H * CW * 4;    // 25.6 MB
    unsigned* pl    = (unsigned*)q;          q += (size_t)8 * CW * 4;
    unsigned* ph    = (unsigned*)q;          q += (size_t)8 * CW * 4;
    unsigned* pcc   = (unsigned*)q;          q += (size_t)NBLK_H * NC * 4 + 1024;
    unsigned* curoff= (unsigned*)q;          q += (size_t)NBLK_H * NC * 4 + 1024;
    char* p = q;
    const size_t SB = 401408;
    unsigned* totals = (unsigned*)(p + 0 * SB);
    int*   cbase   = (int*)(p + 1 * SB);
    int*   row_ptr = (int*)(p + 2 * SB);
    float* nout    = (float*)(p + 3 * SB);
    float* nin     = (float*)(p + 4 * SB);
    _Float16* Wt0  = (_Float16*)(p + 5 * SB);              // 128 KB (pre-swizzled)
    _Float16* Wt1  = (_Float16*)(p + 5 * SB + 131072);
    _Float16* Wt2  = (_Float16*)(p + 5 * SB + 262144);     // 32 KB

    const int AGG_BLOCKS = (NN * 64 + 255) / 256;
    const int SW_BLOCKS  = ((NN + 7) / 8 * 64 + 255) / 256;   // 8 nodes/wave
    const int GB = (NN + 255) / 256;

    // ---- CSR build ----
    hist_k<<<NBLK_H, 512, 0, stream>>>(src, dst, pcnt, pcc);
    {
        dim3 rg((CW + 255) / 256, 8);
        redA_k<<<rg, 256, 0, stream>>>(pcnt, pl, ph);
    }
    nout2_k<<<(CW + 255) / 256, 256, 0, stream>>>(pl, ph, nout);
    offsets_k<<<NC, 256, 0, stream>>>(pcc, curoff, totals);
    base_k<<<1, 512, 0, stream>>>(totals, cbase);
    p1scat_k<<<NBLK_H, 512, 0, stream>>>(src, dst, cbase, curoff, ebuf);
    p2build_k<<<NC, 512, 0, stream>>>(cbase, ebuf, csr_src, row_ptr, nin);

    // ---- fused one-time conversions ----
    {
        int total = NN * 64 + 147456;
        conv_fused_k<<<(total + 255) / 256, 256, 0, stream>>>(
            (const float4*)features, nout, (h4*)hB, W0, W1, W2, Wt0, Wt1, Wt2);
    }

    // ---- layer 0: range-swept agg (A) -> gemm ----
    agg256sw_k<<<SW_BLOCKS, 256, 0, stream>>>(row_ptr, csr_src, hB, hA, NN);
    gemm0_k<<<GB, 1024, 0, stream>>>(hA, Wt0, hB, NN, nin, nout, b0);

    // ---- layer 1: control agg (B) -> fused gemm12 ----
    agg256h_k<<<AGG_BLOCKS, 256, 0, stream>>>(row_ptr, csr_src, hB, hA, NN);
    gemm12_k<<<GB, 1024, 0, stream>>>(hA, Wt1, Wt2, t3h, NN, nin, nout, b1);

    // ---- final aggregation + epilogue ----
    agg64h_k<<<AGG_BLOCKS, 256, 0, stream>>>(row_ptr, csr_src, t3h, nin, b2, out, NN);
}